// Round 14
// baseline (859.567 us; speedup 1.0000x reference)
//
#include <hip/hip_runtime.h>
#include <math.h>

typedef float f32x4 __attribute__((ext_vector_type(4)));
typedef short short8 __attribute__((ext_vector_type(8)));

__device__ __forceinline__ float silu_f(float x) { return x / (1.f + __expf(-x)); }

__device__ __forceinline__ unsigned short f2bf(float x) {
    unsigned u = __float_as_uint(x);
    unsigned r = (u + 0x7fffu + ((u >> 16) & 1u)) >> 16;
    return (unsigned short)r;
}

// ---------------- fused node_pre (f32 xs/xv) + hist (grid-sectioned) ----------------
__global__ __launch_bounds__(256) void k_pre_hist(
    const float* __restrict__ nf, const float* __restrict__ W1s, const float* __restrict__ W1v,
    float* __restrict__ xs, float* __restrict__ xv,
    const int* __restrict__ ei, int* __restrict__ deg,
    int nN, int nE, int nPreBlocks)
{
    __shared__ float s_lds[4][64];
    __shared__ float v_lds[4][96];
    if ((int)blockIdx.x < nPreBlocks) {
        int w = threadIdx.x >> 6, l = threadIdx.x & 63;
        int node = blockIdx.x * 4 + w;
        if (node < nN) {
            const float* row = nf + (long)node * 160;
            s_lds[w][l] = row[l];
            v_lds[w][l] = row[64 + l];
            if (l < 32) v_lds[w][64 + l] = row[128 + l];
        }
        __syncthreads();
        if (node >= nN) return;
        float a = 0.f;
        #pragma unroll 8
        for (int i = 0; i < 64; ++i) a += s_lds[w][i] * W1s[i * 64 + l];
        xs[(long)node * 64 + l] = a * 0.125f;

        int k = l >> 1, c = l & 1;
        float b = 0.f;
        #pragma unroll 8
        for (int m = 0; m < 32; ++m) b += v_lds[w][m * 3 + c] * W1v[m * 32 + k];
        xv[(long)node * 96 + k * 3 + c] = b * 0.17677669529663687f;
        if (l < 32) {
            float d = 0.f;
            #pragma unroll 8
            for (int m = 0; m < 32; ++m) d += v_lds[w][m * 3 + 2] * W1v[m * 32 + l];
            xv[(long)node * 96 + l * 3 + 2] = d * 0.17677669529663687f;
        }
    } else {
        int e = (blockIdx.x - nPreBlocks) * 256 + threadIdx.x;
        if (e < nE) atomicAdd(&deg[ei[nE + e]], 1);
    }
}

// ---------------- sort: scan / scatter ----------------
__global__ __launch_bounds__(256) void k_scan1(const int* __restrict__ deg, int* __restrict__ incl,
                                               int* __restrict__ partials, int nN)
{
    __shared__ int lds[256];
    int t = threadIdx.x;
    int base = blockIdx.x * 1024;
    int v[4]; int s = 0;
    #pragma unroll
    for (int q = 0; q < 4; ++q) { int idx = base + t * 4 + q; v[q] = (idx < nN) ? deg[idx] : 0; s += v[q]; }
    lds[t] = s; __syncthreads();
    #pragma unroll
    for (int off = 1; off < 256; off <<= 1) {
        int x = (t >= off) ? lds[t - off] : 0;
        __syncthreads();
        lds[t] += x;
        __syncthreads();
    }
    int inclT = lds[t];
    if (t == 255) partials[blockIdx.x] = inclT;
    int run = inclT - s;
    #pragma unroll
    for (int q = 0; q < 4; ++q) { run += v[q]; int idx = base + t * 4 + q; if (idx < nN) incl[idx] = run; }
}

__global__ __launch_bounds__(256) void k_scan3(const int* __restrict__ incl, const int* __restrict__ deg,
                                               const int* __restrict__ partials,
                                               int* __restrict__ offs, int* __restrict__ cursor,
                                               int nN, int nb)
{
    __shared__ int part[64];
    int t = threadIdx.x;
    if (t < nb) part[t] = partials[t];
    __syncthreads();
    int i = blockIdx.x * 256 + t;
    if (i < nN) {
        int pidx = i >> 10;
        int pre = 0;
        for (int k = 0; k < pidx; ++k) pre += part[k];
        int excl = incl[i] - deg[i] + pre;
        offs[i] = excl; cursor[i] = excl;
    }
}

__global__ __launch_bounds__(256) void k_scatter(const int* __restrict__ ei, int* __restrict__ cursor,
                                                 int* __restrict__ sorted, int nE)
{
    int e = blockIdx.x * 256 + threadIdx.x;
    if (e < nE) {
        int d = ei[nE + e];
        int pos = atomicAdd(&cursor[d], 1);
        sorted[pos] = e;
    }
}

// ---------------- gather with MFMA layer-2; fast path (deg<=16) = 2 barriers ----------------
__global__ __launch_bounds__(256, 5) void k_gather_mfma(
    const float* __restrict__ esh, const float* __restrict__ eemb,
    const float* __restrict__ fcw1, const float* __restrict__ fcb1,
    const float* __restrict__ fcw2, const float* __restrict__ fcb2,
    const int* __restrict__ ei,
    const float* __restrict__ xs, const float* __restrict__ xv,
    const int* __restrict__ offs, const int* __restrict__ deg,
    const int* __restrict__ sorted, float* __restrict__ agg, int nN)
{
    __shared__ unsigned short hid_lds[2][1024];  // [16 edges][64 hid] bf16, XOR-swizzled
    __shared__ float meta[2][16][20];            // [e]: 0=src 1-4=sh*qdeg 8-15=ee
    __shared__ float xsv[2][16][164];            // staged xs(64)+xv(96) f32 per edge (+pad)

    const int t = threadIdx.x;
    const int l = t & 63;
    const int w = t >> 6;
    const int lr = l & 15;
    const int lg = l >> 4;

    const int myh = l;
    float w1r[8];
    #pragma unroll
    for (int b = 0; b < 8; ++b) w1r[b] = fcw1[b * 64 + myh];
    const float b1r = fcb1[myh];

    short8 bfrag[3][2];
    #pragma unroll
    for (int tt = 0; tt < 3; ++tt) {
        int j = w * 48 + tt * 16 + lr;
        #pragma unroll
        for (int kk = 0; kk < 2; ++kk) {
            short8 f;
            #pragma unroll
            for (int b = 0; b < 8; ++b) {
                int k = kk * 32 + lg * 8 + b;
                f[b] = (short)f2bf(fcw2[k * 192 + j]);
            }
            bfrag[tt][kk] = f;
        }
    }

    const float qdeg = 0.25f;  // 1/sqrt(avg_deg=16)
    const float inv_s3 = 0.57735026918962576f;

    int fp = 0;   // fast-path buffer parity

    for (int node = blockIdx.x; node < nN; node += gridDim.x) {
        const int start = offs[node];
        const int cnt = deg[node];

        float acc[3][3];
        #pragma unroll
        for (int tt = 0; tt < 3; ++tt) { acc[tt][0] = 0.f; acc[tt][1] = 0.f; acc[tt][2] = 0.f; }

        if (cnt > 0 && cnt <= 16) {
            // ---------- FAST PATH: single batch, 2 barriers, parity buffers ----------
            const int buf = fp;
            if (t < 16) {
                int i = t;
                bool valid = i < cnt;
                int eid = sorted[start + (valid ? i : 0)];
                int s_ = ei[eid];
                float4 sh = make_float4(0.f, 0.f, 0.f, 0.f);
                if (valid) sh = *(const float4*)(esh + (size_t)eid * 4);
                float* m = &meta[buf][t][0];
                m[0] = __int_as_float(s_);
                m[1] = sh.x * qdeg; m[2] = sh.y * qdeg; m[3] = sh.z * qdeg; m[4] = sh.w * qdeg;
                const float4* pe = (const float4*)(eemb + (size_t)eid * 8);
                *(float4*)(m + 8)  = pe[0];
                *(float4*)(m + 12) = pe[1];
            }
            __syncthreads();   // meta ready

            // layer-1 + xsv stage (both read meta[buf])
            #pragma unroll
            for (int q = 0; q < 4; ++q) {
                int e = w * 4 + q;
                const float* m = &meta[buf][e][0];
                float a = b1r;
                a += m[8]  * w1r[0] + m[9]  * w1r[1] + m[10] * w1r[2] + m[11] * w1r[3];
                a += m[12] * w1r[4] + m[13] * w1r[5] + m[14] * w1r[6] + m[15] * w1r[7];
                float s = a / (1.f + __expf(-a));
                hid_lds[buf][e * 64 + (myh ^ ((e & 7) << 3))] = f2bf(s);
            }
            for (int i = t; i < 640; i += 256) {
                int e = i / 40, p = i - 40 * e;
                int src = __float_as_int(meta[buf][e][0]);
                float4 val;
                int dsto;
                if (p < 16) { val = *(const float4*)(xs + (size_t)src * 64 + p * 4); dsto = p * 4; }
                else        { val = *(const float4*)(xv + (size_t)src * 96 + (p - 16) * 4); dsto = 64 + (p - 16) * 4; }
                *(float4*)&xsv[buf][e][dsto] = val;
            }
            __syncthreads();   // hid + xsv ready

            short8 a0 = *(const short8*)&hid_lds[buf][lr * 64 + ((lg * 8) ^ ((lr & 7) << 3))];
            short8 a1 = *(const short8*)&hid_lds[buf][lr * 64 + ((32 + lg * 8) ^ ((lr & 7) << 3))];

            f32x4 c0 = {0.f, 0.f, 0.f, 0.f}, c1 = c0, c2 = c0;
            c0 = __builtin_amdgcn_mfma_f32_16x16x32_bf16(a0, bfrag[0][0], c0, 0, 0, 0);
            c0 = __builtin_amdgcn_mfma_f32_16x16x32_bf16(a1, bfrag[0][1], c0, 0, 0, 0);
            c1 = __builtin_amdgcn_mfma_f32_16x16x32_bf16(a0, bfrag[1][0], c1, 0, 0, 0);
            c1 = __builtin_amdgcn_mfma_f32_16x16x32_bf16(a1, bfrag[1][1], c1, 0, 0, 0);
            c2 = __builtin_amdgcn_mfma_f32_16x16x32_bf16(a0, bfrag[2][0], c2, 0, 0, 0);
            c2 = __builtin_amdgcn_mfma_f32_16x16x32_bf16(a1, bfrag[2][1], c2, 0, 0, 0);

            #pragma unroll
            for (int r = 0; r < 4; ++r) {
                int er = lg * 4 + r;
                const float* m = &meta[buf][er][0];
                float sh0 = m[1], s1x = m[2], s1y = m[3], s1z = m[4];
                const float* xr = &xsv[buf][er][0];
                #pragma unroll
                for (int tt = 0; tt < 3; ++tt) {
                    float val = (tt == 0) ? c0[r] : ((tt == 1) ? c1[r] : c2[r]);
                    int rtt = w * 3 + tt;
                    if (rtt < 4) {
                        int j = rtt * 16 + lr;
                        acc[tt][0] += val * xr[j] * sh0;
                    } else if (rtt < 8) {
                        int j = (rtt - 4) * 16 + lr;
                        float tmp = val * xr[j];
                        acc[tt][0] += tmp * s1x; acc[tt][1] += tmp * s1y; acc[tt][2] += tmp * s1z;
                    } else if (rtt < 10) {
                        int k = (rtt - 8) * 16 + lr;
                        float v0 = xr[64 + 3 * k], v1 = xr[64 + 3 * k + 1], v2 = xr[64 + 3 * k + 2];
                        float tmp = val * sh0;
                        acc[tt][0] += tmp * v0; acc[tt][1] += tmp * v1; acc[tt][2] += tmp * v2;
                    } else {
                        int k = (rtt - 10) * 16 + lr;
                        float v0 = xr[64 + 3 * k], v1 = xr[64 + 3 * k + 1], v2 = xr[64 + 3 * k + 2];
                        float dv = v0 * s1x + v1 * s1y + v2 * s1z;
                        acc[tt][0] += val * dv * inv_s3;
                    }
                }
            }
            fp ^= 1;   // no trailing barrier: next node uses the other buffer set
        } else if (cnt > 16) {
            // ---------- SLOW PATH: r11 double-buffered pipeline ----------
            __syncthreads();   // drain possible fast-path reads of buffers
            if (t < 16) {
                int i = t;
                int eid = sorted[start + i];
                int s_ = ei[eid];
                float4 sh = *(const float4*)(esh + (size_t)eid * 4);
                float* m = &meta[0][t][0];
                m[0] = __int_as_float(s_);
                m[1] = sh.x * qdeg; m[2] = sh.y * qdeg; m[3] = sh.z * qdeg; m[4] = sh.w * qdeg;
                const float4* pe = (const float4*)(eemb + (size_t)eid * 8);
                *(float4*)(m + 8)  = pe[0];
                *(float4*)(m + 12) = pe[1];
            }
            __syncthreads();
            for (int i = t; i < 640; i += 256) {
                int e = i / 40, p = i - 40 * e;
                int src = __float_as_int(meta[0][e][0]);
                float4 val;
                int dsto;
                if (p < 16) { val = *(const float4*)(xs + (size_t)src * 64 + p * 4); dsto = p * 4; }
                else        { val = *(const float4*)(xv + (size_t)src * 96 + (p - 16) * 4); dsto = 64 + (p - 16) * 4; }
                *(float4*)&xsv[0][e][dsto] = val;
            }

            int buf = 0;
            for (int i0 = 0; i0 < cnt; i0 += 16) {
                const bool more = (i0 + 16) < cnt;
                if (more && t < 16) {
                    int i = i0 + 16 + t;
                    bool valid = i < cnt;
                    int eid = sorted[start + (valid ? i : 0)];
                    int s_ = ei[eid];
                    float4 sh = make_float4(0.f, 0.f, 0.f, 0.f);
                    if (valid) sh = *(const float4*)(esh + (size_t)eid * 4);
                    float* m = &meta[buf ^ 1][t][0];
                    m[0] = __int_as_float(s_);
                    m[1] = sh.x * qdeg; m[2] = sh.y * qdeg; m[3] = sh.z * qdeg; m[4] = sh.w * qdeg;
                    const float4* pe = (const float4*)(eemb + (size_t)eid * 8);
                    *(float4*)(m + 8)  = pe[0];
                    *(float4*)(m + 12) = pe[1];
                }
                #pragma unroll
                for (int q = 0; q < 4; ++q) {
                    int e = w * 4 + q;
                    const float* m = &meta[buf][e][0];
                    float a = b1r;
                    a += m[8]  * w1r[0] + m[9]  * w1r[1] + m[10] * w1r[2] + m[11] * w1r[3];
                    a += m[12] * w1r[4] + m[13] * w1r[5] + m[14] * w1r[6] + m[15] * w1r[7];
                    float s = a / (1.f + __expf(-a));
                    hid_lds[buf][e * 64 + (myh ^ ((e & 7) << 3))] = f2bf(s);
                }
                __syncthreads();   // hid[buf] + meta[buf^1] ready

                if (more) {
                    for (int i = t; i < 640; i += 256) {
                        int e = i / 40, p = i - 40 * e;
                        int src = __float_as_int(meta[buf ^ 1][e][0]);
                        float4 val;
                        int dsto;
                        if (p < 16) { val = *(const float4*)(xs + (size_t)src * 64 + p * 4); dsto = p * 4; }
                        else        { val = *(const float4*)(xv + (size_t)src * 96 + (p - 16) * 4); dsto = 64 + (p - 16) * 4; }
                        *(float4*)&xsv[buf ^ 1][e][dsto] = val;
                    }
                }

                short8 a0 = *(const short8*)&hid_lds[buf][lr * 64 + ((lg * 8) ^ ((lr & 7) << 3))];
                short8 a1 = *(const short8*)&hid_lds[buf][lr * 64 + ((32 + lg * 8) ^ ((lr & 7) << 3))];

                f32x4 c0 = {0.f, 0.f, 0.f, 0.f}, c1 = c0, c2 = c0;
                c0 = __builtin_amdgcn_mfma_f32_16x16x32_bf16(a0, bfrag[0][0], c0, 0, 0, 0);
                c0 = __builtin_amdgcn_mfma_f32_16x16x32_bf16(a1, bfrag[0][1], c0, 0, 0, 0);
                c1 = __builtin_amdgcn_mfma_f32_16x16x32_bf16(a0, bfrag[1][0], c1, 0, 0, 0);
                c1 = __builtin_amdgcn_mfma_f32_16x16x32_bf16(a1, bfrag[1][1], c1, 0, 0, 0);
                c2 = __builtin_amdgcn_mfma_f32_16x16x32_bf16(a0, bfrag[2][0], c2, 0, 0, 0);
                c2 = __builtin_amdgcn_mfma_f32_16x16x32_bf16(a1, bfrag[2][1], c2, 0, 0, 0);

                #pragma unroll
                for (int r = 0; r < 4; ++r) {
                    int er = lg * 4 + r;
                    const float* m = &meta[buf][er][0];
                    float sh0 = m[1], s1x = m[2], s1y = m[3], s1z = m[4];
                    const float* xr = &xsv[buf][er][0];
                    #pragma unroll
                    for (int tt = 0; tt < 3; ++tt) {
                        float val = (tt == 0) ? c0[r] : ((tt == 1) ? c1[r] : c2[r]);
                        int rtt = w * 3 + tt;
                        if (rtt < 4) {
                            int j = rtt * 16 + lr;
                            acc[tt][0] += val * xr[j] * sh0;
                        } else if (rtt < 8) {
                            int j = (rtt - 4) * 16 + lr;
                            float tmp = val * xr[j];
                            acc[tt][0] += tmp * s1x; acc[tt][1] += tmp * s1y; acc[tt][2] += tmp * s1z;
                        } else if (rtt < 10) {
                            int k = (rtt - 8) * 16 + lr;
                            float v0 = xr[64 + 3 * k], v1 = xr[64 + 3 * k + 1], v2 = xr[64 + 3 * k + 2];
                            float tmp = val * sh0;
                            acc[tt][0] += tmp * v0; acc[tt][1] += tmp * v1; acc[tt][2] += tmp * v2;
                        } else {
                            int k = (rtt - 10) * 16 + lr;
                            float v0 = xr[64 + 3 * k], v1 = xr[64 + 3 * k + 1], v2 = xr[64 + 3 * k + 2];
                            float dv = v0 * s1x + v1 * s1y + v2 * s1z;
                            acc[tt][0] += val * dv * inv_s3;
                        }
                    }
                }
                __syncthreads();   // protect meta[buf]/xsv[buf]
                buf ^= 1;
            }
        }

        // ---- epilogue: reduce across row-groups and write agg row ----
        float* row = agg + (size_t)node * 384;
        #pragma unroll
        for (int tt = 0; tt < 3; ++tt) {
            int rtt = w * 3 + tt;
            if (rtt < 4) {
                float v = acc[tt][0]; v += __shfl_xor(v, 16); v += __shfl_xor(v, 32);
                if (l < 16) row[rtt * 16 + l] = v;
            } else if (rtt < 8) {
                float vx = acc[tt][0]; vx += __shfl_xor(vx, 16); vx += __shfl_xor(vx, 32);
                float vy = acc[tt][1]; vy += __shfl_xor(vy, 16); vy += __shfl_xor(vy, 32);
                float vz = acc[tt][2]; vz += __shfl_xor(vz, 16); vz += __shfl_xor(vz, 32);
                if (l < 16) {
                    int j = (rtt - 4) * 16 + l;
                    row[96 + 3 * j] = vx; row[96 + 3 * j + 1] = vy; row[96 + 3 * j + 2] = vz;
                }
            } else if (rtt < 10) {
                float vx = acc[tt][0]; vx += __shfl_xor(vx, 16); vx += __shfl_xor(vx, 32);
                float vy = acc[tt][1]; vy += __shfl_xor(vy, 16); vy += __shfl_xor(vy, 32);
                float vz = acc[tt][2]; vz += __shfl_xor(vz, 16); vz += __shfl_xor(vz, 32);
                if (l < 16) {
                    int k = (rtt - 8) * 16 + l;
                    row[288 + 3 * k] = vx; row[288 + 3 * k + 1] = vy; row[288 + 3 * k + 2] = vz;
                }
            } else {
                float v = acc[tt][0]; v += __shfl_xor(v, 16); v += __shfl_xor(v, 32);
                if (l < 16) row[64 + (rtt - 10) * 16 + l] = v;
            }
        }
    }
}

// ---------------- node post: split-path, 2 nodes per 384-thread block ----------------
__global__ __launch_bounds__(384) void k_node_post(
    const float* __restrict__ nf, const float* __restrict__ agg,
    const float* __restrict__ W2s, const float* __restrict__ W2v,
    const float* __restrict__ Wscs, const float* __restrict__ Wscv,
    float* __restrict__ out, int n)
{
    __shared__ float ag[2][384];
    __shared__ float sv[2][160];
    __shared__ float gsrc[2][32];
    int half = threadIdx.x / 192;
    int u = threadIdx.x - half * 192;
    int node = blockIdx.x * 2 + half;
    bool active = node < n;
    if (active) {
        for (int i = u; i < 384; i += 192) ag[half][i] = agg[(long)node * 384 + i];
        for (int i = u; i < 160; i += 192) sv[half][i] = nf[(long)node * 160 + i];
    }
    __syncthreads();

    const float c96 = 0.10206207261596577f;  // 1/sqrt(96)
    float osv = 0.f, ovv = 0.f;
    int k = 0, c = 0;
    if (active) {
        if (u < 96) {
            float a = 0.f;
            #pragma unroll 4
            for (int i = 0; i < 96; ++i) a += ag[half][i] * W2s[i * 96 + u];
            float b = 0.f;
            #pragma unroll 4
            for (int i = 0; i < 64; ++i) b += sv[half][i] * Wscs[i * 96 + u];
            osv = a * c96 + b * 0.125f;
            if (u >= 64) gsrc[half][u - 64] = osv;
        } else {
            int uu = u - 96;
            k = uu & 31; c = uu >> 5;
            float av = 0.f;
            #pragma unroll 4
            for (int m = 0; m < 96; ++m) av += ag[half][96 + 3 * m + c] * W2v[m * 32 + k];
            float bv = 0.f;
            #pragma unroll 4
            for (int m = 0; m < 32; ++m) bv += sv[half][64 + 3 * m + c] * Wscv[m * 32 + k];
            ovv = av * c96 + bv * 0.17677669529663687f;
        }
    }
    __syncthreads();
    if (active) {
        if (u < 64) out[(long)node * 160 + u] = sv[half][u] + silu_f(osv);
        else if (u >= 96) {
            float g = silu_f(gsrc[half][k]);
            out[(long)node * 160 + 64 + 3 * k + c] = sv[half][64 + 3 * k + c] + ovv * g;
        }
    }
}

extern "C" void kernel_launch(void* const* d_in, const int* in_sizes, int n_in,
                              void* d_out, int out_size, void* d_ws, size_t ws_size,
                              hipStream_t stream)
{
    const float* nf   = (const float*)d_in[0];
    const float* esh  = (const float*)d_in[1];
    const float* eemb = (const float*)d_in[2];
    const float* W1s  = (const float*)d_in[3];
    const float* W1v  = (const float*)d_in[4];
    const float* fcw1 = (const float*)d_in[5];
    const float* fcb1 = (const float*)d_in[6];
    const float* fcw2 = (const float*)d_in[7];
    const float* fcb2 = (const float*)d_in[8];
    const float* W2s  = (const float*)d_in[9];
    const float* W2v  = (const float*)d_in[10];
    const float* Wscs = (const float*)d_in[11];
    const float* Wscv = (const float*)d_in[12];
    const int*   ei   = (const int*)d_in[13];
    float* out = (float*)d_out;

    int nN = in_sizes[0] / 160;
    int nE = in_sizes[13] / 2;

    // proven ~113 MB layout
    float* xs   = (float*)d_ws;
    float* xv   = xs + (size_t)nN * 64;
    float* agg  = xv + (size_t)nN * 96;
    int* deg    = (int*)(agg + (size_t)nN * 384);
    int* offs   = deg + nN;
    int* cursor = offs + nN;
    int* incl   = cursor + nN;
    int* sorted = incl + nN;
    int* partials = sorted + nE;

    int nb1 = (nN + 1023) / 1024;
    int nPreBlocks = (nN + 3) / 4;
    int nHistBlocks = (nE + 255) / 256;

    hipMemsetAsync(deg, 0, (size_t)nN * sizeof(int), stream);
    k_pre_hist<<<nPreBlocks + nHistBlocks, 256, 0, stream>>>(nf, W1s, W1v, xs, xv, ei, deg, nN, nE, nPreBlocks);
    k_scan1<<<nb1, 256, 0, stream>>>(deg, incl, partials, nN);
    k_scan3<<<(nN + 255) / 256, 256, 0, stream>>>(incl, deg, partials, offs, cursor, nN, nb1);
    k_scatter<<<(nE + 255) / 256, 256, 0, stream>>>(ei, cursor, sorted, nE);
    k_gather_mfma<<<2560, 256, 0, stream>>>(esh, eemb, fcw1, fcb1, fcw2, fcb2, ei,
                                            xs, xv, offs, deg, sorted, agg, nN);
    k_node_post<<<(nN + 1) / 2, 384, 0, stream>>>(nf, agg, W2s, W2v, Wscs, Wscv, out, nN);
}

// Round 15
// 588.021 us; speedup vs baseline: 1.4618x; 1.4618x over previous
//
#include <hip/hip_runtime.h>
#include <math.h>

typedef float f32x4 __attribute__((ext_vector_type(4)));
typedef short short8 __attribute__((ext_vector_type(8)));

__device__ __forceinline__ float silu_f(float x) { return x / (1.f + __expf(-x)); }

__device__ __forceinline__ unsigned short f2bf(float x) {
    unsigned u = __float_as_uint(x);
    unsigned r = (u + 0x7fffu + ((u >> 16) & 1u)) >> 16;
    return (unsigned short)r;
}

// ---------------- fused node_pre (f32 xs/xv) + hist (grid-sectioned) ----------------
__global__ __launch_bounds__(256) void k_pre_hist(
    const float* __restrict__ nf, const float* __restrict__ W1s, const float* __restrict__ W1v,
    float* __restrict__ xs, float* __restrict__ xv,
    const int* __restrict__ ei, int* __restrict__ deg,
    int nN, int nE, int nPreBlocks)
{
    __shared__ float s_lds[4][64];
    __shared__ float v_lds[4][96];
    if ((int)blockIdx.x < nPreBlocks) {
        int w = threadIdx.x >> 6, l = threadIdx.x & 63;
        int node = blockIdx.x * 4 + w;
        if (node < nN) {
            const float* row = nf + (long)node * 160;
            s_lds[w][l] = row[l];
            v_lds[w][l] = row[64 + l];
            if (l < 32) v_lds[w][64 + l] = row[128 + l];
        }
        __syncthreads();
        if (node >= nN) return;
        float a = 0.f;
        #pragma unroll 8
        for (int i = 0; i < 64; ++i) a += s_lds[w][i] * W1s[i * 64 + l];
        xs[(long)node * 64 + l] = a * 0.125f;

        int k = l >> 1, c = l & 1;
        float b = 0.f;
        #pragma unroll 8
        for (int m = 0; m < 32; ++m) b += v_lds[w][m * 3 + c] * W1v[m * 32 + k];
        xv[(long)node * 96 + k * 3 + c] = b * 0.17677669529663687f;
        if (l < 32) {
            float d = 0.f;
            #pragma unroll 8
            for (int m = 0; m < 32; ++m) d += v_lds[w][m * 3 + 2] * W1v[m * 32 + l];
            xv[(long)node * 96 + l * 3 + 2] = d * 0.17677669529663687f;
        }
    } else {
        int e = (blockIdx.x - nPreBlocks) * 256 + threadIdx.x;
        if (e < nE) atomicAdd(&deg[ei[nE + e]], 1);
    }
}

// ---------------- sort: scan / scatter ----------------
__global__ __launch_bounds__(256) void k_scan1(const int* __restrict__ deg, int* __restrict__ incl,
                                               int* __restrict__ partials, int nN)
{
    __shared__ int lds[256];
    int t = threadIdx.x;
    int base = blockIdx.x * 1024;
    int v[4]; int s = 0;
    #pragma unroll
    for (int q = 0; q < 4; ++q) { int idx = base + t * 4 + q; v[q] = (idx < nN) ? deg[idx] : 0; s += v[q]; }
    lds[t] = s; __syncthreads();
    #pragma unroll
    for (int off = 1; off < 256; off <<= 1) {
        int x = (t >= off) ? lds[t - off] : 0;
        __syncthreads();
        lds[t] += x;
        __syncthreads();
    }
    int inclT = lds[t];
    if (t == 255) partials[blockIdx.x] = inclT;
    int run = inclT - s;
    #pragma unroll
    for (int q = 0; q < 4; ++q) { run += v[q]; int idx = base + t * 4 + q; if (idx < nN) incl[idx] = run; }
}

__global__ __launch_bounds__(256) void k_scan3(const int* __restrict__ incl, const int* __restrict__ deg,
                                               const int* __restrict__ partials,
                                               int* __restrict__ offs, int* __restrict__ cursor,
                                               int nN, int nb)
{
    __shared__ int part[64];
    int t = threadIdx.x;
    if (t < nb) part[t] = partials[t];
    __syncthreads();
    int i = blockIdx.x * 256 + t;
    if (i < nN) {
        int pidx = i >> 10;
        int pre = 0;
        for (int k = 0; k < pidx; ++k) pre += part[k];
        int excl = incl[i] - deg[i] + pre;
        offs[i] = excl; cursor[i] = excl;
    }
}

__global__ __launch_bounds__(256) void k_scatter(const int* __restrict__ ei, int* __restrict__ cursor,
                                                 int* __restrict__ sorted, int nE)
{
    int e = blockIdx.x * 256 + threadIdx.x;
    if (e < nE) {
        int d = ei[nE + e];
        int pos = atomicAdd(&cursor[d], 1);
        sorted[pos] = e;
    }
}

// ---------------- gather with MFMA layer-2 (r11 verbatim) ----------------
__global__ __launch_bounds__(256, 5) void k_gather_mfma(
    const float* __restrict__ esh, const float* __restrict__ eemb,
    const float* __restrict__ fcw1, const float* __restrict__ fcb1,
    const float* __restrict__ fcw2, const float* __restrict__ fcb2,
    const int* __restrict__ ei,
    const float* __restrict__ xs, const float* __restrict__ xv,
    const int* __restrict__ offs, const int* __restrict__ deg,
    const int* __restrict__ sorted, float* __restrict__ agg, int nN)
{
    __shared__ unsigned short hid_lds[2][1024];
    __shared__ float meta[2][16][20];
    __shared__ float xsv[2][16][164];

    const int t = threadIdx.x;
    const int l = t & 63;
    const int w = t >> 6;
    const int lr = l & 15;
    const int lg = l >> 4;

    const int myh = l;
    float w1r[8];
    #pragma unroll
    for (int b = 0; b < 8; ++b) w1r[b] = fcw1[b * 64 + myh];
    const float b1r = fcb1[myh];

    short8 bfrag[3][2];
    #pragma unroll
    for (int tt = 0; tt < 3; ++tt) {
        int j = w * 48 + tt * 16 + lr;
        #pragma unroll
        for (int kk = 0; kk < 2; ++kk) {
            short8 f;
            #pragma unroll
            for (int b = 0; b < 8; ++b) {
                int k = kk * 32 + lg * 8 + b;
                f[b] = (short)f2bf(fcw2[k * 192 + j]);
            }
            bfrag[tt][kk] = f;
        }
    }

    const float qdeg = 0.25f;
    const float inv_s3 = 0.57735026918962576f;

    for (int node = blockIdx.x; node < nN; node += gridDim.x) {
        const int start = offs[node];
        const int cnt = deg[node];

        float acc[3][3];
        #pragma unroll
        for (int tt = 0; tt < 3; ++tt) { acc[tt][0] = 0.f; acc[tt][1] = 0.f; acc[tt][2] = 0.f; }

        if (cnt > 0) {
            if (t < 16) {
                int i = t;
                bool valid = i < cnt;
                int eid = sorted[start + (valid ? i : 0)];
                int s_ = ei[eid];
                float4 sh = make_float4(0.f, 0.f, 0.f, 0.f);
                if (valid) sh = *(const float4*)(esh + (size_t)eid * 4);
                float* m = &meta[0][t][0];
                m[0] = __int_as_float(s_);
                m[1] = sh.x * qdeg; m[2] = sh.y * qdeg; m[3] = sh.z * qdeg; m[4] = sh.w * qdeg;
                const float4* pe = (const float4*)(eemb + (size_t)eid * 8);
                *(float4*)(m + 8)  = pe[0];
                *(float4*)(m + 12) = pe[1];
            }
            __syncthreads();
            for (int i = t; i < 640; i += 256) {
                int e = i / 40, p = i - 40 * e;
                int src = __float_as_int(meta[0][e][0]);
                float4 val;
                int dsto;
                if (p < 16) { val = *(const float4*)(xs + (size_t)src * 64 + p * 4); dsto = p * 4; }
                else        { val = *(const float4*)(xv + (size_t)src * 96 + (p - 16) * 4); dsto = 64 + (p - 16) * 4; }
                *(float4*)&xsv[0][e][dsto] = val;
            }
        }

        int buf = 0;
        for (int i0 = 0; i0 < cnt; i0 += 16) {
            const bool more = (i0 + 16) < cnt;
            if (more && t < 16) {
                int i = i0 + 16 + t;
                bool valid = i < cnt;
                int eid = sorted[start + (valid ? i : 0)];
                int s_ = ei[eid];
                float4 sh = make_float4(0.f, 0.f, 0.f, 0.f);
                if (valid) sh = *(const float4*)(esh + (size_t)eid * 4);
                float* m = &meta[buf ^ 1][t][0];
                m[0] = __int_as_float(s_);
                m[1] = sh.x * qdeg; m[2] = sh.y * qdeg; m[3] = sh.z * qdeg; m[4] = sh.w * qdeg;
                const float4* pe = (const float4*)(eemb + (size_t)eid * 8);
                *(float4*)(m + 8)  = pe[0];
                *(float4*)(m + 12) = pe[1];
            }
            #pragma unroll
            for (int q = 0; q < 4; ++q) {
                int e = w * 4 + q;
                const float* m = &meta[buf][e][0];
                float a = b1r;
                a += m[8]  * w1r[0] + m[9]  * w1r[1] + m[10] * w1r[2] + m[11] * w1r[3];
                a += m[12] * w1r[4] + m[13] * w1r[5] + m[14] * w1r[6] + m[15] * w1r[7];
                float s = a / (1.f + __expf(-a));
                hid_lds[buf][e * 64 + (myh ^ ((e & 7) << 3))] = f2bf(s);
            }
            __syncthreads();

            if (more) {
                for (int i = t; i < 640; i += 256) {
                    int e = i / 40, p = i - 40 * e;
                    int src = __float_as_int(meta[buf ^ 1][e][0]);
                    float4 val;
                    int dsto;
                    if (p < 16) { val = *(const float4*)(xs + (size_t)src * 64 + p * 4); dsto = p * 4; }
                    else        { val = *(const float4*)(xv + (size_t)src * 96 + (p - 16) * 4); dsto = 64 + (p - 16) * 4; }
                    *(float4*)&xsv[buf ^ 1][e][dsto] = val;
                }
            }

            short8 a0 = *(const short8*)&hid_lds[buf][lr * 64 + ((lg * 8) ^ ((lr & 7) << 3))];
            short8 a1 = *(const short8*)&hid_lds[buf][lr * 64 + ((32 + lg * 8) ^ ((lr & 7) << 3))];

            f32x4 c0 = {0.f, 0.f, 0.f, 0.f}, c1 = c0, c2 = c0;
            c0 = __builtin_amdgcn_mfma_f32_16x16x32_bf16(a0, bfrag[0][0], c0, 0, 0, 0);
            c0 = __builtin_amdgcn_mfma_f32_16x16x32_bf16(a1, bfrag[0][1], c0, 0, 0, 0);
            c1 = __builtin_amdgcn_mfma_f32_16x16x32_bf16(a0, bfrag[1][0], c1, 0, 0, 0);
            c1 = __builtin_amdgcn_mfma_f32_16x16x32_bf16(a1, bfrag[1][1], c1, 0, 0, 0);
            c2 = __builtin_amdgcn_mfma_f32_16x16x32_bf16(a0, bfrag[2][0], c2, 0, 0, 0);
            c2 = __builtin_amdgcn_mfma_f32_16x16x32_bf16(a1, bfrag[2][1], c2, 0, 0, 0);

            #pragma unroll
            for (int r = 0; r < 4; ++r) {
                int er = lg * 4 + r;
                const float* m = &meta[buf][er][0];
                float sh0 = m[1], s1x = m[2], s1y = m[3], s1z = m[4];
                const float* xr = &xsv[buf][er][0];
                #pragma unroll
                for (int tt = 0; tt < 3; ++tt) {
                    float val = (tt == 0) ? c0[r] : ((tt == 1) ? c1[r] : c2[r]);
                    int rtt = w * 3 + tt;
                    if (rtt < 4) {
                        int j = rtt * 16 + lr;
                        acc[tt][0] += val * xr[j] * sh0;
                    } else if (rtt < 8) {
                        int j = (rtt - 4) * 16 + lr;
                        float tmp = val * xr[j];
                        acc[tt][0] += tmp * s1x; acc[tt][1] += tmp * s1y; acc[tt][2] += tmp * s1z;
                    } else if (rtt < 10) {
                        int k = (rtt - 8) * 16 + lr;
                        float v0 = xr[64 + 3 * k], v1 = xr[64 + 3 * k + 1], v2 = xr[64 + 3 * k + 2];
                        float tmp = val * sh0;
                        acc[tt][0] += tmp * v0; acc[tt][1] += tmp * v1; acc[tt][2] += tmp * v2;
                    } else {
                        int k = (rtt - 10) * 16 + lr;
                        float v0 = xr[64 + 3 * k], v1 = xr[64 + 3 * k + 1], v2 = xr[64 + 3 * k + 2];
                        float dv = v0 * s1x + v1 * s1y + v2 * s1z;
                        acc[tt][0] += val * dv * inv_s3;
                    }
                }
            }
            __syncthreads();
            buf ^= 1;
        }

        float* row = agg + (size_t)node * 384;
        #pragma unroll
        for (int tt = 0; tt < 3; ++tt) {
            int rtt = w * 3 + tt;
            if (rtt < 4) {
                float v = acc[tt][0]; v += __shfl_xor(v, 16); v += __shfl_xor(v, 32);
                if (l < 16) row[rtt * 16 + l] = v;
            } else if (rtt < 8) {
                float vx = acc[tt][0]; vx += __shfl_xor(vx, 16); vx += __shfl_xor(vx, 32);
                float vy = acc[tt][1]; vy += __shfl_xor(vy, 16); vy += __shfl_xor(vy, 32);
                float vz = acc[tt][2]; vz += __shfl_xor(vz, 16); vz += __shfl_xor(vz, 32);
                if (l < 16) {
                    int j = (rtt - 4) * 16 + l;
                    row[96 + 3 * j] = vx; row[96 + 3 * j + 1] = vy; row[96 + 3 * j + 2] = vz;
                }
            } else if (rtt < 10) {
                float vx = acc[tt][0]; vx += __shfl_xor(vx, 16); vx += __shfl_xor(vx, 32);
                float vy = acc[tt][1]; vy += __shfl_xor(vy, 16); vy += __shfl_xor(vy, 32);
                float vz = acc[tt][2]; vz += __shfl_xor(vz, 16); vz += __shfl_xor(vz, 32);
                if (l < 16) {
                    int k = (rtt - 8) * 16 + l;
                    row[288 + 3 * k] = vx; row[288 + 3 * k + 1] = vy; row[288 + 3 * k + 2] = vz;
                }
            } else {
                float v = acc[tt][0]; v += __shfl_xor(v, 16); v += __shfl_xor(v, 32);
                if (l < 16) row[64 + (rtt - 10) * 16 + l] = v;
            }
        }
    }
}

// ---------------- node post via MFMA ----------------
// Per 16-node group: osv[16x96] = [ag_s|s][16x160] @ BsT, ovv[48x32] = [ag_v|v][48x128] @ BvT.
// 12 col/row tiles over 4 waves (3 each). Gates via LDS. Residuals re-read f32.
__global__ __launch_bounds__(256, 2) void k_post_mfma(
    const float* __restrict__ nf, const float* __restrict__ agg,
    const float* __restrict__ W2s, const float* __restrict__ W2v,
    const float* __restrict__ Wscs, const float* __restrict__ Wscv,
    float* __restrict__ out, int nN)
{
    __shared__ unsigned short BsT[96 * 168];   // [j][k] prescaled bf16
    __shared__ unsigned short BvT[32 * 136];
    __shared__ unsigned short As[16 * 168];    // [n][k] bf16
    __shared__ unsigned short Av[48 * 136];    // [c*16+n][k] bf16
    __shared__ float gs[16 * 33];              // gate sources osv[:,64:96]

    const int t = threadIdx.x;
    const int l = t & 63;
    const int w = t >> 6;
    const int lr = l & 15;
    const int lg = l >> 4;

    const float c96 = 0.10206207261596577f;
    const float c64 = 0.125f;
    const float c32 = 0.17677669529663687f;

    // stage B panels once per block (prescaled)
    for (int i = t; i < 160 * 96; i += 256) {
        int k = i / 96, j = i - 96 * k;
        float v = (k < 96) ? W2s[k * 96 + j] * c96 : Wscs[(k - 96) * 96 + j] * c64;
        BsT[j * 168 + k] = f2bf(v);
    }
    for (int i = t; i < 128 * 32; i += 256) {
        int k = i / 32, j = i - 32 * k;
        float v = (k < 96) ? W2v[k * 32 + j] * c96 : Wscv[(k - 96) * 32 + j] * c32;
        BvT[j * 136 + k] = f2bf(v);
    }

    const int nG = (nN + 15) / 16;
    for (int g = blockIdx.x; g < nG; g += gridDim.x) {
        const int node0 = g * 16;
        __syncthreads();   // B ready (first iter) / prior group's gate-reads done

        // stage A (bf16)
        for (int i = t; i < 16 * 160; i += 256) {
            int n = i / 160, k = i - 160 * n;
            int node = node0 + n; if (node >= nN) node = nN - 1;
            float v = (k < 96) ? agg[(size_t)node * 384 + k] : nf[(size_t)node * 160 + (k - 96)];
            As[n * 168 + k] = f2bf(v);
        }
        for (int i = t; i < 48 * 128; i += 256) {
            int row = i / 128, k = i - 128 * row;
            int c = row / 16, n = row - 16 * c;
            int node = node0 + n; if (node >= nN) node = nN - 1;
            float v = (k < 96) ? agg[(size_t)node * 384 + 96 + 3 * k + c]
                               : nf[(size_t)node * 160 + 64 + 3 * (k - 96) + c];
            Av[row * 136 + k] = f2bf(v);
        }
        __syncthreads();   // A ready

        f32x4 accv[3];
        int vmeta[3];      // packed (cdx<<1)|h for v-tiles, -1 otherwise
        #pragma unroll
        for (int tt = 0; tt < 3; ++tt) {
            int T = w * 3 + tt;
            f32x4 c = {0.f, 0.f, 0.f, 0.f};
            if (T < 6) {
                int jb = T * 16;
                #pragma unroll
                for (int ks = 0; ks < 5; ++ks) {
                    short8 a = *(const short8*)&As[lr * 168 + ks * 32 + lg * 8];
                    short8 b = *(const short8*)&BsT[(jb + lr) * 168 + ks * 32 + lg * 8];
                    c = __builtin_amdgcn_mfma_f32_16x16x32_bf16(a, b, c, 0, 0, 0);
                }
                if (jb < 64) {
                    // direct scalar outputs
                    #pragma unroll
                    for (int r = 0; r < 4; ++r) {
                        int n = lg * 4 + r;
                        int node = node0 + n;
                        if (node < nN) {
                            int j = jb + lr;
                            out[(size_t)node * 160 + j] = nf[(size_t)node * 160 + j] + silu_f(c[r]);
                        }
                    }
                } else {
                    // gate source columns
                    #pragma unroll
                    for (int r = 0; r < 4; ++r) {
                        int n = lg * 4 + r;
                        gs[n * 33 + (jb - 64) + lr] = c[r];
                    }
                }
                vmeta[tt] = -1;
                accv[tt] = c;
            } else {
                int vt = T - 6;
                int cdx = vt >> 1, h = vt & 1;
                int kb = h * 16;
                #pragma unroll
                for (int ks = 0; ks < 4; ++ks) {
                    short8 a = *(const short8*)&Av[(cdx * 16 + lr) * 136 + ks * 32 + lg * 8];
                    short8 b = *(const short8*)&BvT[(kb + lr) * 136 + ks * 32 + lg * 8];
                    c = __builtin_amdgcn_mfma_f32_16x16x32_bf16(a, b, c, 0, 0, 0);
                }
                vmeta[tt] = (cdx << 1) | h;
                accv[tt] = c;
            }
        }
        __syncthreads();   // gates ready

        #pragma unroll
        for (int tt = 0; tt < 3; ++tt) {
            if (vmeta[tt] >= 0) {
                int cdx = vmeta[tt] >> 1, h = vmeta[tt] & 1;
                int kb = h * 16;
                f32x4 c = accv[tt];
                #pragma unroll
                for (int r = 0; r < 4; ++r) {
                    int n = lg * 4 + r;
                    int node = node0 + n;
                    if (node < nN) {
                        int k = kb + lr;
                        float gq = silu_f(gs[n * 33 + k]);
                        int o = 64 + 3 * k + cdx;
                        out[(size_t)node * 160 + o] = nf[(size_t)node * 160 + o] + c[r] * gq;
                    }
                }
            }
        }
    }
}

extern "C" void kernel_launch(void* const* d_in, const int* in_sizes, int n_in,
                              void* d_out, int out_size, void* d_ws, size_t ws_size,
                              hipStream_t stream)
{
    const float* nf   = (const float*)d_in[0];
    const float* esh  = (const float*)d_in[1];
    const float* eemb = (const float*)d_in[2];
    const float* W1s  = (const float*)d_in[3];
    const float* W1v  = (const float*)d_in[4];
    const float* fcw1 = (const float*)d_in[5];
    const float* fcb1 = (const float*)d_in[6];
    const float* fcw2 = (const float*)d_in[7];
    const float* fcb2 = (const float*)d_in[8];
    const float* W2s  = (const float*)d_in[9];
    const float* W2v  = (const float*)d_in[10];
    const float* Wscs = (const float*)d_in[11];
    const float* Wscv = (const float*)d_in[12];
    const int*   ei   = (const int*)d_in[13];
    float* out = (float*)d_out;

    int nN = in_sizes[0] / 160;
    int nE = in_sizes[13] / 2;

    // proven ~113 MB layout
    float* xs   = (float*)d_ws;
    float* xv   = xs + (size_t)nN * 64;
    float* agg  = xv + (size_t)nN * 96;
    int* deg    = (int*)(agg + (size_t)nN * 384);
    int* offs   = deg + nN;
    int* cursor = offs + nN;
    int* incl   = cursor + nN;
    int* sorted = incl + nN;
    int* partials = sorted + nE;

    int nb1 = (nN + 1023) / 1024;
    int nPreBlocks = (nN + 3) / 4;
    int nHistBlocks = (nE + 255) / 256;

    hipMemsetAsync(deg, 0, (size_t)nN * sizeof(int), stream);
    k_pre_hist<<<nPreBlocks + nHistBlocks, 256, 0, stream>>>(nf, W1s, W1v, xs, xv, ei, deg, nN, nE, nPreBlocks);
    k_scan1<<<nb1, 256, 0, stream>>>(deg, incl, partials, nN);
    k_scan3<<<(nN + 255) / 256, 256, 0, stream>>>(incl, deg, partials, offs, cursor, nN, nb1);
    k_scatter<<<(nE + 255) / 256, 256, 0, stream>>>(ei, cursor, sorted, nE);
    k_gather_mfma<<<2560, 256, 0, stream>>>(esh, eemb, fcw1, fcb1, fcw2, fcb2, ei,
                                            xs, xv, offs, deg, sorted, agg, nN);
    k_post_mfma<<<512, 256, 0, stream>>>(nf, agg, W2s, W2v, Wscs, Wscv, out, nN);
}